// Round 1
// baseline (214.048 us; speedup 1.0000x reference)
//
#include <hip/hip_runtime.h>
#include <hip/hip_bf16.h>

#define BS 16
#define LQ 300
#define DIM 256
#define NH 8
#define HD 32
#define SUMP 16
#define LV 8500
#define NQ (BS*LQ)       // 4800
#define MROWS (BS*LV)    // 136000

typedef __bf16 bf16x8 __attribute__((ext_vector_type(8)));
typedef float f32x4 __attribute__((ext_vector_type(4)));

__device__ __forceinline__ unsigned f2bf1(float f) {
    unsigned u = __float_as_uint(f);
    return (u + 0x7fffu + ((u >> 16) & 1u)) >> 16;   // RNE
}
__device__ __forceinline__ float bf2f(unsigned short u) {
    return __uint_as_float(((unsigned)u) << 16);
}

// ---------------- K1: v_bf16 = bf16( value @ W_val^T + b_val ) -----------
// 128x128 tile, BK=32, 4 waves, 16x16x32 bf16 MFMA. Reg-staged fp32->bf16.
__global__ __launch_bounds__(256) void k_val_gemm(
    const float* __restrict__ value, const float* __restrict__ Wv,
    const float* __restrict__ bv, unsigned short* __restrict__ vout)
{
    __shared__ unsigned short Alds[128 * 32];
    __shared__ unsigned short Blds[128 * 32];
    const int t = threadIdx.x;
    const int bm = blockIdx.x, bn = blockIdx.y;
    const int lane = t & 63, wid = t >> 6;
    const int wm = (wid >> 1) * 64, wn = (wid & 1) * 64;

    f32x4 acc[4][4] = {};

    const int rA0 = t >> 2;          // 0..63
    const int kk = (t & 3) * 8;      // 0,8,16,24

    for (int kt = 0; kt < 8; ++kt) {
        __syncthreads();
        const int k0 = kt * 32 + kk;
        #pragma unroll
        for (int c = 0; c < 2; ++c) {
            long gr = (long)bm * 128 + c * 64 + rA0;
            if (gr > MROWS - 1) gr = MROWS - 1;
            const float* pa = value + gr * 256 + k0;
            float4 a0 = *(const float4*)pa;
            float4 a1 = *(const float4*)(pa + 4);
            uint4 ua;
            ua.x = f2bf1(a0.x) | (f2bf1(a0.y) << 16);
            ua.y = f2bf1(a0.z) | (f2bf1(a0.w) << 16);
            ua.z = f2bf1(a1.x) | (f2bf1(a1.y) << 16);
            ua.w = f2bf1(a1.z) | (f2bf1(a1.w) << 16);
            *(uint4*)&Alds[c * 2048 + t * 8] = ua;

            const int nr = bn * 128 + c * 64 + rA0;   // < 256 always
            const float* pb = Wv + (long)nr * 256 + k0;
            float4 b0 = *(const float4*)pb;
            float4 b1 = *(const float4*)(pb + 4);
            uint4 ub;
            ub.x = f2bf1(b0.x) | (f2bf1(b0.y) << 16);
            ub.y = f2bf1(b0.z) | (f2bf1(b0.w) << 16);
            ub.z = f2bf1(b1.x) | (f2bf1(b1.y) << 16);
            ub.w = f2bf1(b1.z) | (f2bf1(b1.w) << 16);
            *(uint4*)&Blds[c * 2048 + t * 8] = ub;
        }
        __syncthreads();

        const int koff = (lane >> 4) * 8;
        bf16x8 af[4], bfr[4];
        #pragma unroll
        for (int i = 0; i < 4; ++i)
            af[i] = *(const bf16x8*)&Alds[(wm + i * 16 + (lane & 15)) * 32 + koff];
        #pragma unroll
        for (int j = 0; j < 4; ++j)
            bfr[j] = *(const bf16x8*)&Blds[(wn + j * 16 + (lane & 15)) * 32 + koff];
        #pragma unroll
        for (int i = 0; i < 4; ++i)
            #pragma unroll
            for (int j = 0; j < 4; ++j)
                acc[i][j] = __builtin_amdgcn_mfma_f32_16x16x32_bf16(af[i], bfr[j], acc[i][j], 0, 0, 0);
    }

    // epilogue: D[row][col]: col = lane&15, row = (lane>>4)*4 + r   [verified layout]
    #pragma unroll
    for (int j = 0; j < 4; ++j) {
        const int col = bn * 128 + wn + j * 16 + (lane & 15);
        const float bias = bv[col];
        #pragma unroll
        for (int i = 0; i < 4; ++i) {
            #pragma unroll
            for (int r = 0; r < 4; ++r) {
                long row = (long)bm * 128 + wm + i * 16 + (lane >> 4) * 4 + r;
                if (row < MROWS) {
                    float v = acc[i][j][r] + bias;
                    vout[row * 256 + col] = (unsigned short)f2bf1(v);
                }
            }
        }
    }
}

// ---------------- K2: off/attn projections + softmax + sampling locs ----
__global__ __launch_bounds__(384) void k_offattn(
    const float* __restrict__ query, const float* __restrict__ refp,
    const float* __restrict__ Woff, const float* __restrict__ boff,
    const float* __restrict__ Wattn, const float* __restrict__ battn,
    float* __restrict__ loc, float* __restrict__ aw)
{
    __shared__ float qlds[8][256];
    __shared__ float res[8][384];
    const int t = threadIdx.x;
    const int qg0 = blockIdx.x * 8;

    for (int idx = t; idx < 2048; idx += 384)
        ((float*)qlds)[idx] = query[(long)qg0 * 256 + idx];
    __syncthreads();

    const float* wrow = (t < 256) ? (Woff + (long)t * 256) : (Wattn + (long)(t - 256) * 256);
    float acc[8] = {0.f, 0.f, 0.f, 0.f, 0.f, 0.f, 0.f, 0.f};
    for (int k4 = 0; k4 < 64; ++k4) {
        float4 w = *(const float4*)(wrow + k4 * 4);
        #pragma unroll
        for (int q = 0; q < 8; ++q) {
            float4 qv = *(const float4*)&qlds[q][k4 * 4];
            acc[q] += w.x * qv.x + w.y * qv.y + w.z * qv.z + w.w * qv.w;
        }
    }
    const float bias = (t < 256) ? boff[t] : battn[t - 256];
    #pragma unroll
    for (int q = 0; q < 8; ++q) res[q][t] = acc[q] + bias;
    __syncthreads();

    if (t < 64) {
        const int q = t >> 3, h = t & 7;
        const int qg = qg0 + q;
        const float rx = refp[qg * 4 + 0], ry = refp[qg * 4 + 1];
        const float rz = refp[qg * 4 + 2], rw = refp[qg * 4 + 3];
        float m = -1e30f;
        #pragma unroll
        for (int p = 0; p < 16; ++p) m = fmaxf(m, res[q][256 + h * 16 + p]);
        float e[16]; float s = 0.f;
        #pragma unroll
        for (int p = 0; p < 16; ++p) { e[p] = expf(res[q][256 + h * 16 + p] - m); s += e[p]; }
        const float inv = 1.f / s;
        const float sx = 0.25f * rz * 0.5f, sy = 0.25f * rw * 0.5f;
        #pragma unroll
        for (int p = 0; p < 16; ++p) {
            const float ox = res[q][(h * 16 + p) * 2], oy = res[q][(h * 16 + p) * 2 + 1];
            const long base = (long)(qg * 8 + h) * 16 + p;
            loc[base * 2 + 0] = rx + ox * sx;
            loc[base * 2 + 1] = ry + oy * sy;
            aw[base] = e[p] * inv;
        }
    }
}

// ---------------- K3: bilinear sampling + attention-weighted sum ---------
__global__ __launch_bounds__(256) void k_sample(
    const unsigned short* __restrict__ vbf, const float* __restrict__ loc,
    const float* __restrict__ aw, float* __restrict__ sampled)
{
    const int t = threadIdx.x;
    const int wid = t >> 6, lane = t & 63;
    const int id = blockIdx.x * 4 + wid;   // qg*8 + h, 38400 total
    const int h = id & 7;
    const int qg = id >> 3;
    const int b = qg / LQ;
    const int c2 = lane & 31;
    const int half = lane >> 5;

    const unsigned short* vb = vbf + (long)b * LV * 256 + h * 32 + c2;
    const float* locp = loc + (long)id * SUMP * 2;
    const float* awp = aw + (long)id * SUMP;

    const int WLs[4] = {80, 40, 20, 10};
    const int SVs[4] = {0, 6400, 8000, 8400};

    float acc = 0.f;
    #pragma unroll
    for (int pp = 0; pp < 8; ++pp) {
        const int lvl = pp >> 1;               // pair never straddles a level
        const int Wl = WLs[lvl], Hl = WLs[lvl];
        const unsigned short* base = vb + (long)SVs[lvl] * 256;
        const int p = pp * 2 + half;
        const float lx = locp[p * 2], ly = locp[p * 2 + 1];
        const float aww = awp[p];
        const float x = lx * Wl - 0.5f, y = ly * Hl - 0.5f;
        const float x0f = floorf(x), y0f = floorf(y);
        const float wx = x - x0f, wy = y - y0f;
        const int x0 = (int)x0f, y0 = (int)y0f;
        #pragma unroll
        for (int dy = 0; dy < 2; ++dy) {
            const int yi = y0 + dy;
            if (yi < 0 || yi >= Hl) continue;
            const float wyv = dy ? wy : 1.f - wy;
            #pragma unroll
            for (int dx = 0; dx < 2; ++dx) {
                const int xi = x0 + dx;
                if (xi < 0 || xi >= Wl) continue;
                const float wxv = dx ? wx : 1.f - wx;
                acc += aww * wyv * wxv * bf2f(base[((long)yi * Wl + xi) * 256]);
            }
        }
    }
    acc += __shfl_xor(acc, 32);
    if (half == 0) sampled[(long)qg * 256 + h * 32 + c2] = acc;
}

// ---------------- K4: out = sampled @ W_out^T + b_out --------------------
__global__ __launch_bounds__(256) void k_out(
    const float* __restrict__ sampled, const float* __restrict__ Wout,
    const float* __restrict__ bout, float* __restrict__ out)
{
    __shared__ float slds[8][256];
    const int t = threadIdx.x;
    const int qg0 = blockIdx.x * 8;
    for (int idx = t; idx < 2048; idx += 256)
        ((float*)slds)[idx] = sampled[(long)qg0 * 256 + idx];
    __syncthreads();

    const float* wrow = Wout + (long)t * 256;
    float acc[8] = {0.f, 0.f, 0.f, 0.f, 0.f, 0.f, 0.f, 0.f};
    for (int k4 = 0; k4 < 64; ++k4) {
        float4 w = *(const float4*)(wrow + k4 * 4);
        #pragma unroll
        for (int q = 0; q < 8; ++q) {
            float4 s = *(const float4*)&slds[q][k4 * 4];
            acc[q] += w.x * s.x + w.y * s.y + w.z * s.z + w.w * s.w;
        }
    }
    const float bias = bout[t];
    #pragma unroll
    for (int q = 0; q < 8; ++q)
        out[(long)(qg0 + q) * 256 + t] = acc[q] + bias;
}

extern "C" void kernel_launch(void* const* d_in, const int* in_sizes, int n_in,
                              void* d_out, int out_size, void* d_ws, size_t ws_size,
                              hipStream_t stream)
{
    const float* query = (const float*)d_in[0];
    const float* refp  = (const float*)d_in[1];
    const float* value = (const float*)d_in[2];
    const float* Woff  = (const float*)d_in[3];
    const float* boff  = (const float*)d_in[4];
    const float* Wattn = (const float*)d_in[5];
    const float* battn = (const float*)d_in[6];
    const float* Wval  = (const float*)d_in[7];
    const float* bval  = (const float*)d_in[8];
    const float* Wout  = (const float*)d_in[9];
    const float* bout  = (const float*)d_in[10];

    char* ws = (char*)d_ws;
    unsigned short* vbf = (unsigned short*)ws;                 // 69,632,000 B
    float* sampled = (float*)(ws + 69632000);                  //  4,915,200 B
    float* loc     = (float*)(ws + 69632000 + 4915200);        //  4,915,200 B
    float* aw      = (float*)(ws + 69632000 + 2 * 4915200);    //  2,457,600 B

    hipLaunchKernelGGL(k_val_gemm, dim3(1063, 2), dim3(256), 0, stream,
                       value, Wval, bval, vbf);
    hipLaunchKernelGGL(k_offattn, dim3(600), dim3(384), 0, stream,
                       query, refp, Woff, boff, Wattn, battn, loc, aw);
    hipLaunchKernelGGL(k_sample, dim3(9600), dim3(256), 0, stream,
                       vbf, loc, aw, sampled);
    hipLaunchKernelGGL(k_out, dim3(600), dim3(256), 0, stream,
                       sampled, Wout, bout, (float*)d_out);
}

// Round 2
// 212.287 us; speedup vs baseline: 1.0083x; 1.0083x over previous
//
#include <hip/hip_runtime.h>
#include <hip/hip_bf16.h>

#define BS 16
#define LQ 300
#define DIM 256
#define NH 8
#define HD 32
#define SUMP 16
#define LV 8500
#define NQ (BS*LQ)       // 4800
#define MROWS (BS*LV)    // 136000
#define RS 40            // padded LDS row stride (shorts) = 80B, kills stride-64B bank conflicts

typedef __bf16 bf16x8 __attribute__((ext_vector_type(8)));
typedef float f32x4 __attribute__((ext_vector_type(4)));

__device__ __forceinline__ unsigned f2bf1(float f) {
    unsigned u = __float_as_uint(f);
    return (u + 0x7fffu + ((u >> 16) & 1u)) >> 16;   // RNE
}
__device__ __forceinline__ float bf2f(unsigned short u) {
    return __uint_as_float(((unsigned)u) << 16);
}
// 8 fp32 -> 8 bf16 (16B). Plain casts so the compiler emits v_cvt_pk_bf16_f32.
__device__ __forceinline__ uint4 cvt16B(float4 a, float4 b) {
    bf16x8 r;
    r[0] = (__bf16)a.x; r[1] = (__bf16)a.y; r[2] = (__bf16)a.z; r[3] = (__bf16)a.w;
    r[4] = (__bf16)b.x; r[5] = (__bf16)b.y; r[6] = (__bf16)b.z; r[7] = (__bf16)b.w;
    return *(uint4*)&r;
}

// ---------------- K1: v_bf16 = bf16( value @ W_val^T + b_val ) -----------
// 128x128 tile, BK=32, 4 waves, 16x16x32 bf16 MFMA.
// Double-buffered LDS, prefetch-issue before MFMA, convert+ds_write after,
// one barrier per K-step. LDS-staged coalesced bf16 epilogue.
__global__ __launch_bounds__(256) void k_val_gemm(
    const float* __restrict__ value, const float* __restrict__ Wv,
    const float* __restrict__ bv, unsigned short* __restrict__ vout)
{
    __shared__ unsigned short SH[20480];   // A0,A1,B0,B1 (128*RS each) = 40KB
    unsigned short* const A0 = SH;
    unsigned short* const A1 = SH + 5120;
    unsigned short* const B0 = SH + 10240;
    unsigned short* const B1 = SH + 15360;

    const int t = threadIdx.x;
    const int bm = blockIdx.x, bn = blockIdx.y;
    const int lane = t & 63, wid = t >> 6;
    const int wm = (wid >> 1) * 64, wn = (wid & 1) * 64;

    f32x4 acc[4][4] = {};

    // staging: thread t covers A/B row (t>>1), k-cols (t&1)*16 .. +15
    const int srow = t >> 1;
    const int skol = (t & 1) * 16;
    long gr = (long)bm * 128 + srow; if (gr >= MROWS) gr = MROWS - 1;
    const float* pa = value + gr * 256;
    const float* pb = Wv + ((long)bn * 128 + srow) * 256;

    // prologue: stage K-tile 0 into buf0
    {
        float4 na[4], nb[4];
        #pragma unroll
        for (int u = 0; u < 4; ++u) {
            na[u] = *(const float4*)(pa + skol + u * 4);
            nb[u] = *(const float4*)(pb + skol + u * 4);
        }
        *(uint4*)&A0[srow * RS + skol]     = cvt16B(na[0], na[1]);
        *(uint4*)&A0[srow * RS + skol + 8] = cvt16B(na[2], na[3]);
        *(uint4*)&B0[srow * RS + skol]     = cvt16B(nb[0], nb[1]);
        *(uint4*)&B0[srow * RS + skol + 8] = cvt16B(nb[2], nb[3]);
    }
    __syncthreads();

    const int koff = (lane >> 4) * 8;
    const int fra = (lane & 15);

#define STEP(Ac, Bc, An, Bn, KT)                                               \
    {                                                                          \
        float4 na[4], nb[4];                                                   \
        if ((KT) < 7) {                                                        \
            const int k0 = ((KT) + 1) * 32 + skol;                             \
            _Pragma("unroll")                                                  \
            for (int u = 0; u < 4; ++u) {                                      \
                na[u] = *(const float4*)(pa + k0 + u * 4);                     \
                nb[u] = *(const float4*)(pb + k0 + u * 4);                     \
            }                                                                  \
        }                                                                      \
        bf16x8 af[4], bfv[4];                                                  \
        _Pragma("unroll")                                                      \
        for (int i = 0; i < 4; ++i)                                            \
            af[i] = *(const bf16x8*)&Ac[(wm + i * 16 + fra) * RS + koff];      \
        _Pragma("unroll")                                                      \
        for (int j = 0; j < 4; ++j)                                            \
            bfv[j] = *(const bf16x8*)&Bc[(wn + j * 16 + fra) * RS + koff];     \
        _Pragma("unroll")                                                      \
        for (int i = 0; i < 4; ++i)                                            \
            _Pragma("unroll")                                                  \
            for (int j = 0; j < 4; ++j)                                        \
                acc[i][j] = __builtin_amdgcn_mfma_f32_16x16x32_bf16(           \
                    af[i], bfv[j], acc[i][j], 0, 0, 0);                        \
        if ((KT) < 7) {                                                        \
            *(uint4*)&An[srow * RS + skol]     = cvt16B(na[0], na[1]);         \
            *(uint4*)&An[srow * RS + skol + 8] = cvt16B(na[2], na[3]);         \
            *(uint4*)&Bn[srow * RS + skol]     = cvt16B(nb[0], nb[1]);         \
            *(uint4*)&Bn[srow * RS + skol + 8] = cvt16B(nb[2], nb[3]);         \
        }                                                                      \
        __syncthreads();                                                       \
    }

    STEP(A0, B0, A1, B1, 0)
    STEP(A1, B1, A0, B0, 1)
    STEP(A0, B0, A1, B1, 2)
    STEP(A1, B1, A0, B0, 3)
    STEP(A0, B0, A1, B1, 4)
    STEP(A1, B1, A0, B0, 5)
    STEP(A0, B0, A1, B1, 6)
    STEP(A1, B1, A0, B0, 7)
#undef STEP

    // epilogue: acc -> SH as C[128][128] bf16, then coalesced 256B/row stores
    #pragma unroll
    for (int j = 0; j < 4; ++j) {
        const int col = wn + j * 16 + fra;
        const float bias = bv[bn * 128 + col];
        #pragma unroll
        for (int i = 0; i < 4; ++i) {
            const int r0 = wm + i * 16 + (lane >> 4) * 4;
            #pragma unroll
            for (int r = 0; r < 4; ++r) {
                __bf16 bb = (__bf16)(acc[i][j][r] + bias);
                SH[(r0 + r) * 128 + col] = *(unsigned short*)&bb;
            }
        }
    }
    __syncthreads();
    {
        const int row = t >> 1, half = t & 1;
        const long grow = (long)bm * 128 + row;
        if (grow < MROWS) {
            const uint4* src = (const uint4*)&SH[row * 128 + half * 64];
            uint4* dst = (uint4*)&vout[grow * 256 + bn * 128 + half * 64];
            #pragma unroll
            for (int u = 0; u < 8; ++u) dst[u] = src[u];
        }
    }
}

// ---------------- K2: off/attn projections + softmax + sampling locs ----
__global__ __launch_bounds__(384) void k_offattn(
    const float* __restrict__ query, const float* __restrict__ refp,
    const float* __restrict__ Woff, const float* __restrict__ boff,
    const float* __restrict__ Wattn, const float* __restrict__ battn,
    float* __restrict__ loc, float* __restrict__ aw)
{
    __shared__ float qlds[8][256];
    __shared__ float res[8][384];
    const int t = threadIdx.x;
    const int qg0 = blockIdx.x * 8;

    for (int idx = t; idx < 2048; idx += 384)
        ((float*)qlds)[idx] = query[(long)qg0 * 256 + idx];
    __syncthreads();

    const float* wrow = (t < 256) ? (Woff + (long)t * 256) : (Wattn + (long)(t - 256) * 256);
    float acc[8] = {0.f, 0.f, 0.f, 0.f, 0.f, 0.f, 0.f, 0.f};
    for (int k4 = 0; k4 < 64; ++k4) {
        float4 w = *(const float4*)(wrow + k4 * 4);
        #pragma unroll
        for (int q = 0; q < 8; ++q) {
            float4 qv = *(const float4*)&qlds[q][k4 * 4];
            acc[q] += w.x * qv.x + w.y * qv.y + w.z * qv.z + w.w * qv.w;
        }
    }
    const float bias = (t < 256) ? boff[t] : battn[t - 256];
    #pragma unroll
    for (int q = 0; q < 8; ++q) res[q][t] = acc[q] + bias;
    __syncthreads();

    if (t < 64) {
        const int q = t >> 3, h = t & 7;
        const int qg = qg0 + q;
        const float rx = refp[qg * 4 + 0], ry = refp[qg * 4 + 1];
        const float rz = refp[qg * 4 + 2], rw = refp[qg * 4 + 3];
        float m = -1e30f;
        #pragma unroll
        for (int p = 0; p < 16; ++p) m = fmaxf(m, res[q][256 + h * 16 + p]);
        float e[16]; float s = 0.f;
        #pragma unroll
        for (int p = 0; p < 16; ++p) { e[p] = expf(res[q][256 + h * 16 + p] - m); s += e[p]; }
        const float inv = 1.f / s;
        const float sx = 0.25f * rz * 0.5f, sy = 0.25f * rw * 0.5f;
        #pragma unroll
        for (int p = 0; p < 16; ++p) {
            const float ox = res[q][(h * 16 + p) * 2], oy = res[q][(h * 16 + p) * 2 + 1];
            const long base = (long)(qg * 8 + h) * 16 + p;
            loc[base * 2 + 0] = rx + ox * sx;
            loc[base * 2 + 1] = ry + oy * sy;
            aw[base] = e[p] * inv;
        }
    }
}

// ---------------- K3: bilinear sampling + attention-weighted sum ---------
__global__ __launch_bounds__(256) void k_sample(
    const unsigned short* __restrict__ vbf, const float* __restrict__ loc,
    const float* __restrict__ aw, float* __restrict__ sampled)
{
    const int t = threadIdx.x;
    const int wid = t >> 6, lane = t & 63;
    const int id = blockIdx.x * 4 + wid;   // qg*8 + h, 38400 total
    const int h = id & 7;
    const int qg = id >> 3;
    const int b = qg / LQ;
    const int c2 = lane & 31;
    const int half = lane >> 5;

    const unsigned short* vb = vbf + (long)b * LV * 256 + h * 32 + c2;
    const float* locp = loc + (long)id * SUMP * 2;
    const float* awp = aw + (long)id * SUMP;

    const int WLs[4] = {80, 40, 20, 10};
    const int SVs[4] = {0, 6400, 8000, 8400};

    float acc = 0.f;
    #pragma unroll
    for (int pp = 0; pp < 8; ++pp) {
        const int lvl = pp >> 1;               // pair never straddles a level
        const int Wl = WLs[lvl], Hl = WLs[lvl];
        const unsigned short* base = vb + (long)SVs[lvl] * 256;
        const int p = pp * 2 + half;
        const float lx = locp[p * 2], ly = locp[p * 2 + 1];
        const float aww = awp[p];
        const float x = lx * Wl - 0.5f, y = ly * Hl - 0.5f;
        const float x0f = floorf(x), y0f = floorf(y);
        const float wx = x - x0f, wy = y - y0f;
        const int x0 = (int)x0f, y0 = (int)y0f;
        #pragma unroll
        for (int dy = 0; dy < 2; ++dy) {
            const int yi = y0 + dy;
            if (yi < 0 || yi >= Hl) continue;
            const float wyv = dy ? wy : 1.f - wy;
            #pragma unroll
            for (int dx = 0; dx < 2; ++dx) {
                const int xi = x0 + dx;
                if (xi < 0 || xi >= Wl) continue;
                const float wxv = dx ? wx : 1.f - wx;
                acc += aww * wyv * wxv * bf2f(base[((long)yi * Wl + xi) * 256]);
            }
        }
    }
    acc += __shfl_xor(acc, 32);
    if (half == 0) sampled[(long)qg * 256 + h * 32 + c2] = acc;
}

// ---------------- K4: out = sampled @ W_out^T + b_out --------------------
__global__ __launch_bounds__(256) void k_out(
    const float* __restrict__ sampled, const float* __restrict__ Wout,
    const float* __restrict__ bout, float* __restrict__ out)
{
    __shared__ float slds[8][256];
    const int t = threadIdx.x;
    const int qg0 = blockIdx.x * 8;
    for (int idx = t; idx < 2048; idx += 256)
        ((float*)slds)[idx] = sampled[(long)qg0 * 256 + idx];
    __syncthreads();

    const float* wrow = Wout + (long)t * 256;
    float acc[8] = {0.f, 0.f, 0.f, 0.f, 0.f, 0.f, 0.f, 0.f};
    for (int k4 = 0; k4 < 64; ++k4) {
        float4 w = *(const float4*)(wrow + k4 * 4);
        #pragma unroll
        for (int q = 0; q < 8; ++q) {
            float4 s = *(const float4*)&slds[q][k4 * 4];
            acc[q] += w.x * s.x + w.y * s.y + w.z * s.z + w.w * s.w;
        }
    }
    const float bias = bout[t];
    #pragma unroll
    for (int q = 0; q < 8; ++q)
        out[(long)(qg0 + q) * 256 + t] = acc[q] + bias;
}

extern "C" void kernel_launch(void* const* d_in, const int* in_sizes, int n_in,
                              void* d_out, int out_size, void* d_ws, size_t ws_size,
                              hipStream_t stream)
{
    const float* query = (const float*)d_in[0];
    const float* refp  = (const float*)d_in[1];
    const float* value = (const float*)d_in[2];
    const float* Woff  = (const float*)d_in[3];
    const float* boff  = (const float*)d_in[4];
    const float* Wattn = (const float*)d_in[5];
    const float* battn = (const float*)d_in[6];
    const float* Wval  = (const float*)d_in[7];
    const float* bval  = (const float*)d_in[8];
    const float* Wout  = (const float*)d_in[9];
    const float* bout  = (const float*)d_in[10];

    char* ws = (char*)d_ws;
    unsigned short* vbf = (unsigned short*)ws;                 // 69,632,000 B
    float* sampled = (float*)(ws + 69632000);                  //  4,915,200 B
    float* loc     = (float*)(ws + 69632000 + 4915200);        //  4,915,200 B
    float* aw      = (float*)(ws + 69632000 + 2 * 4915200);    //  2,457,600 B

    hipLaunchKernelGGL(k_val_gemm, dim3(1063, 2), dim3(256), 0, stream,
                       value, Wval, bval, vbf);
    hipLaunchKernelGGL(k_offattn, dim3(600), dim3(384), 0, stream,
                       query, refp, Woff, boff, Wattn, battn, loc, aw);
    hipLaunchKernelGGL(k_sample, dim3(9600), dim3(256), 0, stream,
                       vbf, loc, aw, sampled);
    hipLaunchKernelGGL(k_out, dim3(600), dim3(256), 0, stream,
                       sampled, Wout, bout, (float*)d_out);
}

// Round 3
// 193.351 us; speedup vs baseline: 1.1070x; 1.0979x over previous
//
#include <hip/hip_runtime.h>
#include <hip/hip_bf16.h>

#define BS 16
#define LQ 300
#define DIM 256
#define NH 8
#define HD 32
#define SUMP 16
#define LV 8500
#define NQ (BS*LQ)       // 4800
#define MROWS (BS*LV)    // 136000
#define RS 40            // staging LDS row stride (shorts) = 80B
#define ES 132           // epilogue C-tile row stride (shorts) = 264B (≡2 mod 32 banks)

typedef __bf16 bf16x4 __attribute__((ext_vector_type(4)));
typedef __bf16 bf16x8 __attribute__((ext_vector_type(8)));
typedef float f32x4 __attribute__((ext_vector_type(4)));

__device__ __forceinline__ float bf2f(unsigned short u) {
    return __uint_as_float(((unsigned)u) << 16);
}
// 4 fp32 -> 4 bf16 (8B); plain casts so compiler emits v_cvt_pk_bf16_f32
__device__ __forceinline__ bf16x4 cvt8B(float4 a) {
    bf16x4 r;
    r[0] = (__bf16)a.x; r[1] = (__bf16)a.y; r[2] = (__bf16)a.z; r[3] = (__bf16)a.w;
    return r;
}

// ---------------- K1: v_bf16 = bf16( value @ W_val^T + b_val ) -----------
// 128x128 tile, BK=32, 4 waves, 16x16x32 bf16 MFMA, double-buffered LDS.
// Coalesced staging (lane-consecutive 16B), swapped-operand MFMA so the
// epilogue packs 4 consecutive n per lane (8B LDS writes, stride-132 tile),
// coalesced 16B global stores.
__global__ __launch_bounds__(256) void k_val_gemm(
    const float* __restrict__ value, const float* __restrict__ Wv,
    const float* __restrict__ bv, unsigned short* __restrict__ vout)
{
    __shared__ unsigned short SH[20480];   // staging: A0,A1,B0,B1 (128*RS each) = 40KB; epilogue reuses as C[128][ES]
    unsigned short* const A0 = SH;
    unsigned short* const A1 = SH + 5120;
    unsigned short* const B0 = SH + 10240;
    unsigned short* const B1 = SH + 15360;

    const int t = threadIdx.x;
    const int bm = blockIdx.x, bn = blockIdx.y;
    const int lane = t & 63, wid = t >> 6;
    const int wm = (wid >> 1) * 64, wn = (wid & 1) * 64;

    f32x4 acc[4][4] = {};

    // coalesced staging: thread t covers row u*32 + (t>>3), floats (t&7)*4..+3
    const int srow = t >> 3;           // 0..31
    const int scol = (t & 7) * 4;      // float index 0..28
    // per-u row byte offsets into value (clamped) and Wv
    unsigned aoff[4];
    const float* pb0 = Wv + ((long)bn * 128 + srow) * 256 + scol;
    #pragma unroll
    for (int u = 0; u < 4; ++u) {
        long gr = (long)bm * 128 + u * 32 + srow;
        if (gr > MROWS - 1) gr = MROWS - 1;
        aoff[u] = (unsigned)(gr * 256 + scol);
    }
    const int lw = srow * RS + scol;   // LDS short offset base (row srow)

    // prologue: stage K-tile 0 into buf0
    {
        #pragma unroll
        for (int u = 0; u < 4; ++u) {
            float4 a = *(const float4*)(value + aoff[u]);
            float4 b = *(const float4*)(pb0 + u * 32 * 256);
            *(bf16x4*)&A0[lw + u * 32 * RS] = cvt8B(a);
            *(bf16x4*)&B0[lw + u * 32 * RS] = cvt8B(b);
        }
    }
    __syncthreads();

    const int koff = (lane >> 4) * 8;
    const int fra = (lane & 15);

#define STEP(Ac, Bc, An, Bn, KT)                                               \
    {                                                                          \
        float4 na[4], nb[4];                                                   \
        if ((KT) < 7) {                                                        \
            const int k0 = ((KT) + 1) * 32;                                    \
            _Pragma("unroll")                                                  \
            for (int u = 0; u < 4; ++u) {                                      \
                na[u] = *(const float4*)(value + aoff[u] + k0);                \
                nb[u] = *(const float4*)(pb0 + u * 32 * 256 + k0);             \
            }                                                                  \
        }                                                                      \
        bf16x8 af[4], bfv[4];                                                  \
        _Pragma("unroll")                                                      \
        for (int i = 0; i < 4; ++i)                                            \
            af[i] = *(const bf16x8*)&Ac[(wm + i * 16 + fra) * RS + koff];      \
        _Pragma("unroll")                                                      \
        for (int j = 0; j < 4; ++j)                                            \
            bfv[j] = *(const bf16x8*)&Bc[(wn + j * 16 + fra) * RS + koff];     \
        _Pragma("unroll")                                                      \
        for (int i = 0; i < 4; ++i)                                            \
            _Pragma("unroll")                                                  \
            for (int j = 0; j < 4; ++j)                                        \
                acc[i][j] = __builtin_amdgcn_mfma_f32_16x16x32_bf16(           \
                    bfv[j], af[i], acc[i][j], 0, 0, 0);  /* swapped: lane holds m=lane&15, 4 consecutive n */ \
        if ((KT) < 7) {                                                        \
            _Pragma("unroll")                                                  \
            for (int u = 0; u < 4; ++u) {                                      \
                *(bf16x4*)&An[lw + u * 32 * RS] = cvt8B(na[u]);                \
                *(bf16x4*)&Bn[lw + u * 32 * RS] = cvt8B(nb[u]);                \
            }                                                                  \
        }                                                                      \
        __syncthreads();                                                       \
    }

    STEP(A0, B0, A1, B1, 0)
    STEP(A1, B1, A0, B0, 1)
    STEP(A0, B0, A1, B1, 2)
    STEP(A1, B1, A0, B0, 3)
    STEP(A0, B0, A1, B1, 4)
    STEP(A1, B1, A0, B0, 5)
    STEP(A0, B0, A1, B1, 6)
    STEP(A1, B1, A0, B0, 7)
#undef STEP

    // epilogue: lane holds C[m][n0..n0+3], m = wm+i*16+(lane&15), n0 = wn+j*16+(lane>>4)*4
    {
        const int nreg = (lane >> 4) * 4;
        #pragma unroll
        for (int j = 0; j < 4; ++j) {
            const float4 bj = *(const float4*)&bv[bn * 128 + wn + j * 16 + nreg];
            #pragma unroll
            for (int i = 0; i < 4; ++i) {
                const int m = wm + i * 16 + fra;
                const int n0 = wn + j * 16 + nreg;
                float4 v;
                v.x = acc[i][j][0] + bj.x;
                v.y = acc[i][j][1] + bj.y;
                v.z = acc[i][j][2] + bj.z;
                v.w = acc[i][j][3] + bj.w;
                *(bf16x4*)&SH[m * ES + n0] = cvt8B(v);
            }
        }
    }
    __syncthreads();
    // coalesced stores: 8 iters, 16B per thread, lanes consecutive within a row
    {
        #pragma unroll
        for (int u = 0; u < 8; ++u) {
            const int f = u * 256 + t;
            const int row = f >> 4;
            const int col = (f & 15) * 8;
            const long grow = (long)bm * 128 + row;
            if (grow < MROWS)
                *(uint4*)&vout[grow * 256 + bn * 128 + col] = *(const uint4*)&SH[row * ES + col];
        }
    }
}

// ---------------- K2: off/attn projections + softmax + sampling locs ----
__global__ __launch_bounds__(384) void k_offattn(
    const float* __restrict__ query, const float* __restrict__ refp,
    const float* __restrict__ Woff, const float* __restrict__ boff,
    const float* __restrict__ Wattn, const float* __restrict__ battn,
    float* __restrict__ loc, float* __restrict__ aw)
{
    __shared__ float qlds[8][256];
    __shared__ float res[8][384];
    const int t = threadIdx.x;
    const int qg0 = blockIdx.x * 8;

    for (int idx = t; idx < 2048; idx += 384)
        ((float*)qlds)[idx] = query[(long)qg0 * 256 + idx];
    __syncthreads();

    const float* wrow = (t < 256) ? (Woff + (long)t * 256) : (Wattn + (long)(t - 256) * 256);
    float acc[8] = {0.f, 0.f, 0.f, 0.f, 0.f, 0.f, 0.f, 0.f};
    for (int k4 = 0; k4 < 64; ++k4) {
        float4 w = *(const float4*)(wrow + k4 * 4);
        #pragma unroll
        for (int q = 0; q < 8; ++q) {
            float4 qv = *(const float4*)&qlds[q][k4 * 4];
            acc[q] += w.x * qv.x + w.y * qv.y + w.z * qv.z + w.w * qv.w;
        }
    }
    const float bias = (t < 256) ? boff[t] : battn[t - 256];
    #pragma unroll
    for (int q = 0; q < 8; ++q) res[q][t] = acc[q] + bias;
    __syncthreads();

    if (t < 64) {
        const int q = t >> 3, h = t & 7;
        const int qg = qg0 + q;
        const float rx = refp[qg * 4 + 0], ry = refp[qg * 4 + 1];
        const float rz = refp[qg * 4 + 2], rw = refp[qg * 4 + 3];
        float m = -1e30f;
        #pragma unroll
        for (int p = 0; p < 16; ++p) m = fmaxf(m, res[q][256 + h * 16 + p]);
        float e[16]; float s = 0.f;
        #pragma unroll
        for (int p = 0; p < 16; ++p) { e[p] = expf(res[q][256 + h * 16 + p] - m); s += e[p]; }
        const float inv = 1.f / s;
        const float sx = 0.25f * rz * 0.5f, sy = 0.25f * rw * 0.5f;
        #pragma unroll
        for (int p = 0; p < 16; ++p) {
            const float ox = res[q][(h * 16 + p) * 2], oy = res[q][(h * 16 + p) * 2 + 1];
            const long base = (long)(qg * 8 + h) * 16 + p;
            loc[base * 2 + 0] = rx + ox * sx;
            loc[base * 2 + 1] = ry + oy * sy;
            aw[base] = e[p] * inv;
        }
    }
}

// ---------------- K3: bilinear sampling + attention-weighted sum ---------
__global__ __launch_bounds__(256) void k_sample(
    const unsigned short* __restrict__ vbf, const float* __restrict__ loc,
    const float* __restrict__ aw, float* __restrict__ sampled)
{
    const int t = threadIdx.x;
    const int wid = t >> 6, lane = t & 63;
    const int id = blockIdx.x * 4 + wid;   // qg*8 + h, 38400 total
    const int h = id & 7;
    const int qg = id >> 3;
    const int b = qg / LQ;
    const int c2 = lane & 31;
    const int half = lane >> 5;

    const unsigned short* vb = vbf + (long)b * LV * 256 + h * 32 + c2;
    const float* locp = loc + (long)id * SUMP * 2;
    const float* awp = aw + (long)id * SUMP;

    const int WLs[4] = {80, 40, 20, 10};
    const int SVs[4] = {0, 6400, 8000, 8400};

    float acc = 0.f;
    #pragma unroll
    for (int pp = 0; pp < 8; ++pp) {
        const int lvl = pp >> 1;               // pair never straddles a level
        const int Wl = WLs[lvl], Hl = WLs[lvl];
        const unsigned short* base = vb + (long)SVs[lvl] * 256;
        const int p = pp * 2 + half;
        const float lx = locp[p * 2], ly = locp[p * 2 + 1];
        const float aww = awp[p];
        const float x = lx * Wl - 0.5f, y = ly * Hl - 0.5f;
        const float x0f = floorf(x), y0f = floorf(y);
        const float wx = x - x0f, wy = y - y0f;
        const int x0 = (int)x0f, y0 = (int)y0f;
        #pragma unroll
        for (int dy = 0; dy < 2; ++dy) {
            const int yi = y0 + dy;
            if (yi < 0 || yi >= Hl) continue;
            const float wyv = dy ? wy : 1.f - wy;
            #pragma unroll
            for (int dx = 0; dx < 2; ++dx) {
                const int xi = x0 + dx;
                if (xi < 0 || xi >= Wl) continue;
                const float wxv = dx ? wx : 1.f - wx;
                acc += aww * wyv * wxv * bf2f(base[((long)yi * Wl + xi) * 256]);
            }
        }
    }
    acc += __shfl_xor(acc, 32);
    if (half == 0) sampled[(long)qg * 256 + h * 32 + c2] = acc;
}

// ---------------- K4: out = sampled @ W_out^T + b_out --------------------
__global__ __launch_bounds__(256) void k_out(
    const float* __restrict__ sampled, const float* __restrict__ Wout,
    const float* __restrict__ bout, float* __restrict__ out)
{
    __shared__ float slds[8][256];
    const int t = threadIdx.x;
    const int qg0 = blockIdx.x * 8;
    for (int idx = t; idx < 2048; idx += 256)
        ((float*)slds)[idx] = sampled[(long)qg0 * 256 + idx];
    __syncthreads();

    const float* wrow = Wout + (long)t * 256;
    float acc[8] = {0.f, 0.f, 0.f, 0.f, 0.f, 0.f, 0.f, 0.f};
    for (int k4 = 0; k4 < 64; ++k4) {
        float4 w = *(const float4*)(wrow + k4 * 4);
        #pragma unroll
        for (int q = 0; q < 8; ++q) {
            float4 s = *(const float4*)&slds[q][k4 * 4];
            acc[q] += w.x * s.x + w.y * s.y + w.z * s.z + w.w * s.w;
        }
    }
    const float bias = bout[t];
    #pragma unroll
    for (int q = 0; q < 8; ++q)
        out[(long)(qg0 + q) * 256 + t] = acc[q] + bias;
}

extern "C" void kernel_launch(void* const* d_in, const int* in_sizes, int n_in,
                              void* d_out, int out_size, void* d_ws, size_t ws_size,
                              hipStream_t stream)
{
    const float* query = (const float*)d_in[0];
    const float* refp  = (const float*)d_in[1];
    const float* value = (const float*)d_in[2];
    const float* Woff  = (const float*)d_in[3];
    const float* boff  = (const float*)d_in[4];
    const float* Wattn = (const float*)d_in[5];
    const float* battn = (const float*)d_in[6];
    const float* Wval  = (const float*)d_in[7];
    const float* bval  = (const float*)d_in[8];
    const float* Wout  = (const float*)d_in[9];
    const float* bout  = (const float*)d_in[10];

    char* ws = (char*)d_ws;
    unsigned short* vbf = (unsigned short*)ws;                 // 69,632,000 B
    float* sampled = (float*)(ws + 69632000);                  //  4,915,200 B
    float* loc     = (float*)(ws + 69632000 + 4915200);        //  4,915,200 B
    float* aw      = (float*)(ws + 69632000 + 2 * 4915200);    //  2,457,600 B

    hipLaunchKernelGGL(k_val_gemm, dim3(1063, 2), dim3(256), 0, stream,
                       value, Wval, bval, vbf);
    hipLaunchKernelGGL(k_offattn, dim3(600), dim3(384), 0, stream,
                       query, refp, Woff, boff, Wattn, battn, loc, aw);
    hipLaunchKernelGGL(k_sample, dim3(9600), dim3(256), 0, stream,
                       vbf, loc, aw, sampled);
    hipLaunchKernelGGL(k_out, dim3(600), dim3(256), 0, stream,
                       sampled, Wout, bout, (float*)d_out);
}